// Round 3
// baseline (335.790 us; speedup 1.0000x reference)
//
#include <hip/hip_runtime.h>
#include <math.h>

typedef __bf16 bf16;
typedef __bf16 bf16x8 __attribute__((ext_vector_type(8)));
typedef float f32x4 __attribute__((ext_vector_type(4)));

#define CC 256
#define BB 16
#define HH 56
#define WW 56
#define HWSZ 3136   // 56*56
#define EPS 1e-5f

// ---------------------------------------------------------------------------
// K0: zero the SE accumulator (graph-capture-safe, no memset)
// ---------------------------------------------------------------------------
__global__ void zero_sums(float* __restrict__ sums) {
    sums[blockIdx.x * 256 + threadIdx.x] = 0.f;
}

// ---------------------------------------------------------------------------
// K1: pw1 GEMM.  out[b,co,hw] = sum_ci w[co,ci] * x[b,ci,hw]
// fp32 in, bf16 MFMA compute, T out (float preferred / bf16 small-ws fallback)
// grid (49, 4, 16) ; block 256 (4 waves). Tile: M=64 co, N=64 hw, K=256.
// ---------------------------------------------------------------------------
template <typename T>
__global__ __launch_bounds__(256) void pw_gemm1(
    const float* __restrict__ in, const float* __restrict__ w,
    T* __restrict__ out)
{
    __shared__ __align__(16) bf16 BT[64][264];   // [hw_local][ci], pad 264
    const int nt  = blockIdx.x;          // hw tile 0..48
    const int mt  = blockIdx.y;          // co tile 0..3
    const int b   = blockIdx.z;
    const int hw0 = nt * 64;
    const int co0 = mt * 64;
    const int tid = threadIdx.x;

    // stage X tile transposed: thread tid owns ci=tid, covers 64 hw
    const float* src = in + (size_t)b * CC * HWSZ + (size_t)tid * HWSZ + hw0;
#pragma unroll
    for (int p = 0; p < 8; ++p) {
        f32x4 v0 = *(const f32x4*)(src + p * 8);
        f32x4 v1 = *(const f32x4*)(src + p * 8 + 4);
#pragma unroll
        for (int j = 0; j < 4; ++j) {
            BT[p * 8 + j][tid]     = (bf16)v0[j];
            BT[p * 8 + 4 + j][tid] = (bf16)v1[j];
        }
    }
    __syncthreads();

    const int lane = tid & 63, wv = tid >> 6;
    const int q = lane >> 4, m = lane & 15;

    f32x4 acc[4] = {};
    const float* wbase = w + (size_t)(co0 + wv * 16 + m) * CC + q * 8;
#pragma unroll
    for (int kk = 0; kk < 8; ++kk) {
        f32x4 a0 = *(const f32x4*)(wbase + kk * 32);
        f32x4 a1 = *(const f32x4*)(wbase + kk * 32 + 4);
        bf16x8 a;
#pragma unroll
        for (int j = 0; j < 4; ++j) { a[j] = (bf16)a0[j]; a[4 + j] = (bf16)a1[j]; }
#pragma unroll
        for (int n = 0; n < 4; ++n) {
            bf16x8 bv = *(const bf16x8*)(&BT[n * 16 + m][kk * 32 + q * 8]);
            acc[n] = __builtin_amdgcn_mfma_f32_16x16x32_bf16(a, bv, acc[n], 0, 0, 0);
        }
    }
    T* obase = out + (size_t)b * CC * HWSZ;
#pragma unroll
    for (int n = 0; n < 4; ++n) {
        const int hw = hw0 + n * 16 + m;
#pragma unroll
        for (int r = 0; r < 4; ++r) {
            const int co = co0 + wv * 16 + q * 4 + r;
            obase[(size_t)co * HWSZ + hw] = (T)acc[n][r];
        }
    }
}

// ---------------------------------------------------------------------------
// K2: fused depthwise branches + BN + ReLU + gate.  One block per (b,c) plane.
// All params fp32; plane input T (float or bf16); writes bf16 top (d_out scratch)
// ---------------------------------------------------------------------------
template <typename T>
__global__ __launch_bounds__(256) void dwfuse(
    const T* __restrict__ in,
    const float* __restrict__ xy3, const float* __restrict__ xy5,
    const float* __restrict__ gxy, const float* __restrict__ bxy,
    const float* __restrict__ mxy, const float* __restrict__ vxy,
    const float* __restrict__ xz3, const float* __restrict__ xz5,
    const float* __restrict__ gxz, const float* __restrict__ bxz,
    const float* __restrict__ mxz, const float* __restrict__ vxz,
    const float* __restrict__ yz3, const float* __restrict__ yz5,
    const float* __restrict__ gyz, const float* __restrict__ byz,
    const float* __restrict__ myz, const float* __restrict__ vyz,
    const float* __restrict__ alpha, const float* __restrict__ beta,
    bf16* __restrict__ top)
{
    __shared__ float T2[60 * 65];   // halo-2 tile, pad 65
    __shared__ float wk[64];
    const int bc  = blockIdx.x;       // b*256 + c
    const int c   = bc & 255;
    const int tid = threadIdx.x;

    const T* plane = in + (size_t)bc * HWSZ;
    for (int li = tid; li < 3600; li += 256) {
        const int r = li / 60, cc2 = li - r * 60;
        const int h = r - 2, w2 = cc2 - 2;
        float v = 0.f;
        if ((unsigned)h < 56u && (unsigned)w2 < 56u) v = (float)plane[h * 56 + w2];
        T2[r * 65 + cc2] = v;
    }
    if (tid < 9)        wk[tid] = xy3[c * 9 + tid];
    else if (tid < 34)  wk[tid] = xy5[c * 25 + (tid - 9)];
    else if (tid < 37)  wk[tid] = xz3[c * 3 + (tid - 34)];
    else if (tid < 42)  wk[tid] = xz5[c * 5 + (tid - 37)];
    else if (tid < 45)  wk[tid] = yz3[c * 3 + (tid - 42)];
    else if (tid < 50)  wk[tid] = yz5[c * 5 + (tid - 45)];
    else if (tid == 50) { float s = gxy[c] * rsqrtf(vxy[c] + EPS);
                          wk[50] = s; wk[51] = bxy[c] - mxy[c] * s; }
    else if (tid == 52) { float s = gxz[c] * rsqrtf(vxz[c] + EPS);
                          wk[52] = s; wk[53] = bxz[c] - mxz[c] * s; }
    else if (tid == 54) { float s = gyz[c] * rsqrtf(vyz[c] + EPS);
                          wk[54] = s; wk[55] = byz[c] - myz[c] * s; }
    else if (tid == 56) { wk[56] = alpha[c]; wk[57] = beta[c]; }
    __syncthreads();

    bf16* tp = top + (size_t)bc * HWSZ;
    for (int li = tid; li < HWSZ; li += 256) {
        const int h = li / 56, w2 = li - h * 56;
        const float* t0 = &T2[h * 65 + w2];
        float axy = 0.f;
#pragma unroll
        for (int kh = 0; kh < 5; ++kh)
#pragma unroll
            for (int kw = 0; kw < 5; ++kw)
                axy += wk[9 + kh * 5 + kw] * t0[kh * 65 + kw];
#pragma unroll
        for (int kh = 0; kh < 3; ++kh)
#pragma unroll
            for (int kw = 0; kw < 3; ++kw)
                axy += wk[kh * 3 + kw] * t0[(kh + 1) * 65 + (kw + 1)];
        float axz = 0.f;
#pragma unroll
        for (int kw = 0; kw < 5; ++kw) axz += wk[37 + kw] * t0[2 * 65 + kw];
#pragma unroll
        for (int kw = 0; kw < 3; ++kw) axz += wk[34 + kw] * t0[2 * 65 + 1 + kw];
        float ayz = 0.f;
#pragma unroll
        for (int kh = 0; kh < 5; ++kh) ayz += wk[45 + kh] * t0[kh * 65 + 2];
#pragma unroll
        for (int kh = 0; kh < 3; ++kh) ayz += wk[42 + kh] * t0[(kh + 1) * 65 + 2];

        const float fxy = fmaxf(axy * wk[50] + wk[51], 0.f);
        const float fxz = fmaxf(axz * wk[52] + wk[53], 0.f);
        const float fyz = fmaxf(ayz * wk[54] + wk[55], 0.f);
        const float z   = wk[56] * fxz + wk[57] * fyz;
        const float g   = 1.f / (1.f + expf(-z));
        tp[li] = (bf16)fmaxf(fxy * g, 0.f);
    }
}

// ---------------------------------------------------------------------------
// K3: pw2 GEMM + BN + ReLU -> out2 (T, into ws) + per-(b,c) spatial sums
// in = top (bf16, in d_out scratch), w fp32 -> bf16 on the fly
// ---------------------------------------------------------------------------
template <typename T>
__global__ __launch_bounds__(256) void pw_gemm2(
    const bf16* __restrict__ in, const float* __restrict__ w,
    const float* __restrict__ g2, const float* __restrict__ b2,
    const float* __restrict__ m2, const float* __restrict__ v2,
    T* __restrict__ out2, float* __restrict__ sums)
{
    __shared__ __align__(16) bf16 BT[64][264];
    const int nt  = blockIdx.x;
    const int mt  = blockIdx.y;
    const int b   = blockIdx.z;
    const int hw0 = nt * 64;
    const int co0 = mt * 64;
    const int tid = threadIdx.x;

    const bf16* src = in + (size_t)b * CC * HWSZ + (size_t)tid * HWSZ + hw0;
#pragma unroll
    for (int p = 0; p < 8; ++p) {
        bf16x8 v = *(const bf16x8*)(src + p * 8);
#pragma unroll
        for (int j = 0; j < 8; ++j) BT[p * 8 + j][tid] = v[j];
    }
    __syncthreads();

    const int lane = tid & 63, wv = tid >> 6;
    const int q = lane >> 4, m = lane & 15;

    f32x4 acc[4] = {};
    const float* wbase = w + (size_t)(co0 + wv * 16 + m) * CC + q * 8;
#pragma unroll
    for (int kk = 0; kk < 8; ++kk) {
        f32x4 a0 = *(const f32x4*)(wbase + kk * 32);
        f32x4 a1 = *(const f32x4*)(wbase + kk * 32 + 4);
        bf16x8 a;
#pragma unroll
        for (int j = 0; j < 4; ++j) { a[j] = (bf16)a0[j]; a[4 + j] = (bf16)a1[j]; }
#pragma unroll
        for (int n = 0; n < 4; ++n) {
            bf16x8 bv = *(const bf16x8*)(&BT[n * 16 + m][kk * 32 + q * 8]);
            acc[n] = __builtin_amdgcn_mfma_f32_16x16x32_bf16(a, bv, acc[n], 0, 0, 0);
        }
    }
    T* obase = out2 + (size_t)b * CC * HWSZ;
#pragma unroll
    for (int r = 0; r < 4; ++r) {
        const int co = co0 + wv * 16 + q * 4 + r;
        const float sc = g2[co] * rsqrtf(v2[co] + EPS);
        const float sh = b2[co] - m2[co] * sc;
        float rs = 0.f;
#pragma unroll
        for (int n = 0; n < 4; ++n) {
            float v = fmaxf(acc[n][r] * sc + sh, 0.f);
            rs += v;
            obase[(size_t)co * HWSZ + hw0 + n * 16 + m] = (T)v;
        }
        // reduce across the 16 lanes sharing (q, r) -> sum over 64 hw
        rs += __shfl_xor(rs, 1);
        rs += __shfl_xor(rs, 2);
        rs += __shfl_xor(rs, 4);
        rs += __shfl_xor(rs, 8);
        if (m == 0) atomicAdd(&sums[b * CC + co], rs);
    }
}

// ---------------------------------------------------------------------------
// K4: SE fully-connected:  scale[b,c] = sigmoid(W2 relu(W1 mean + b1) + b2)
// ---------------------------------------------------------------------------
__global__ __launch_bounds__(256) void se_fc(
    const float* __restrict__ sums,
    const float* __restrict__ w1, const float* __restrict__ b1,
    const float* __restrict__ w2, const float* __restrict__ b2,
    float* __restrict__ scale)
{
    __shared__ float mean[256];
    __shared__ float hid[16];
    const int b = blockIdx.x, tid = threadIdx.x;
    mean[tid] = sums[b * CC + tid] * (1.f / (float)HWSZ);
    __syncthreads();
    if (tid < 16) {
        float h = b1[tid];
        for (int cd = 0; cd < 256; ++cd) h += w1[tid * 256 + cd] * mean[cd];
        hid[tid] = fmaxf(h, 0.f);
    }
    __syncthreads();
    float v = b2[tid];
#pragma unroll
    for (int md = 0; md < 16; ++md) v += w2[tid * 16 + md] * hid[md];
    scale[b * CC + tid] = 1.f / (1.f + expf(-v));
}

// ---------------------------------------------------------------------------
// K5: out = out2 * scale[b,c] + x   (out2 in ws; final fp32 -> d_out)
// ---------------------------------------------------------------------------
template <typename T>
__global__ __launch_bounds__(256) void se_apply(
    const T* __restrict__ out2, const float* __restrict__ x,
    const float* __restrict__ scale, float* __restrict__ out)
{
    const int idx = blockIdx.x * 256 + threadIdx.x;   // 8-elem chunk id
    const size_t base = (size_t)idx * 8;
    const int bc = (int)(base / HWSZ);
    const float s = scale[bc];
    f32x4 x0 = *(const f32x4*)(x + base);
    f32x4 x1 = *(const f32x4*)(x + base + 4);
    f32x4 r0, r1;
#pragma unroll
    for (int j = 0; j < 4; ++j) {
        r0[j] = (float)out2[base + j] * s + x0[j];
        r1[j] = (float)out2[base + 4 + j] * s + x1[j];
    }
    *(f32x4*)(out + base)     = r0;
    *(f32x4*)(out + base + 4) = r1;
}

// ---------------------------------------------------------------------------
extern "C" void kernel_launch(void* const* d_in, const int* in_sizes, int n_in,
                              void* d_out, int out_size, void* d_ws, size_t ws_size,
                              hipStream_t stream)
{
    const float* x      = (const float*)d_in[0];
    const float* pw1_w  = (const float*)d_in[1];
    const float* xy3_w  = (const float*)d_in[2];
    const float* xy5_w  = (const float*)d_in[3];
    const float* bnxy_g = (const float*)d_in[4];
    const float* bnxy_b = (const float*)d_in[5];
    const float* bnxy_m = (const float*)d_in[6];
    const float* bnxy_v = (const float*)d_in[7];
    const float* xz3_w  = (const float*)d_in[8];
    const float* xz5_w  = (const float*)d_in[9];
    const float* bnxz_g = (const float*)d_in[10];
    const float* bnxz_b = (const float*)d_in[11];
    const float* bnxz_m = (const float*)d_in[12];
    const float* bnxz_v = (const float*)d_in[13];
    const float* yz3_w  = (const float*)d_in[14];
    const float* yz5_w  = (const float*)d_in[15];
    const float* bnyz_g = (const float*)d_in[16];
    const float* bnyz_b = (const float*)d_in[17];
    const float* bnyz_m = (const float*)d_in[18];
    const float* bnyz_v = (const float*)d_in[19];
    const float* alpha  = (const float*)d_in[20];
    const float* beta   = (const float*)d_in[21];
    const float* pw2_w  = (const float*)d_in[22];
    const float* bn2_g  = (const float*)d_in[23];
    const float* bn2_b  = (const float*)d_in[24];
    const float* bn2_m  = (const float*)d_in[25];
    const float* bn2_v  = (const float*)d_in[26];
    const float* fc1_w  = (const float*)d_in[27];
    const float* fc1_b  = (const float*)d_in[28];
    const float* fc2_w  = (const float*)d_in[29];
    const float* fc2_b  = (const float*)d_in[30];

    const size_t NEL = (size_t)BB * CC * HWSZ;           // 12,845,056
    float* scale = (float*)d_ws;                         // 16 KB
    float* sums  = scale + BB * CC;                      // 16 KB
    char*  mid   = (char*)d_ws + 32 * 1024;              // pw1 out, then out2
    bf16*  top   = (bf16*)d_out;                         // d_out doubles as scratch
    const bool mid_fp32 = ws_size >= 32 * 1024 + NEL * 4;

    zero_sums<<<BB * CC / 256, 256, 0, stream>>>(sums);

    dim3 gg(49, 4, 16);
    if (mid_fp32) {
        pw_gemm1<float><<<gg, 256, 0, stream>>>(x, pw1_w, (float*)mid);
        dwfuse<float><<<BB * CC, 256, 0, stream>>>((const float*)mid,
            xy3_w, xy5_w, bnxy_g, bnxy_b, bnxy_m, bnxy_v,
            xz3_w, xz5_w, bnxz_g, bnxz_b, bnxz_m, bnxz_v,
            yz3_w, yz5_w, bnyz_g, bnyz_b, bnyz_m, bnyz_v,
            alpha, beta, top);
        pw_gemm2<float><<<gg, 256, 0, stream>>>(top, pw2_w, bn2_g, bn2_b,
                                                bn2_m, bn2_v, (float*)mid, sums);
        se_fc<<<BB, 256, 0, stream>>>(sums, fc1_w, fc1_b, fc2_w, fc2_b, scale);
        se_apply<float><<<(int)(NEL / 8 / 256), 256, 0, stream>>>(
            (const float*)mid, x, scale, (float*)d_out);
    } else {
        pw_gemm1<bf16><<<gg, 256, 0, stream>>>(x, pw1_w, (bf16*)mid);
        dwfuse<bf16><<<BB * CC, 256, 0, stream>>>((const bf16*)mid,
            xy3_w, xy5_w, bnxy_g, bnxy_b, bnxy_m, bnxy_v,
            xz3_w, xz5_w, bnxz_g, bnxz_b, bnxz_m, bnxz_v,
            yz3_w, yz5_w, bnyz_g, bnyz_b, bnyz_m, bnyz_v,
            alpha, beta, top);
        pw_gemm2<bf16><<<gg, 256, 0, stream>>>(top, pw2_w, bn2_g, bn2_b,
                                               bn2_m, bn2_v, (bf16*)mid, sums);
        se_fc<<<BB, 256, 0, stream>>>(sums, fc1_w, fc1_b, fc2_w, fc2_b, scale);
        se_apply<bf16><<<(int)(NEL / 8 / 256), 256, 0, stream>>>(
            (const bf16*)mid, x, scale, (float*)d_out);
    }
}